// Round 3
// 586.522 us; speedup vs baseline: 1.0015x; 1.0015x over previous
//
#include <hip/hip_runtime.h>
#include <math.h>

// Problem constants (fixed by setup_inputs)
#define BD   1024            // batch B
#define LW   80              // walk length L
#define AA   76              // anchors A = L - w + 1, w = 5
#define NEGS 4               // negatives per anchor
#define D    128             // embed dim
#define PAIRS (BD * AA)      // 77824 (b,a) pairs
#define WAVES_PER_BLOCK 4
#define PAIRS_PER_WAVE 19    // 76 = 4 waves x 19 anchors, exact
#define NBLOCKS BD           // one block per batch row

// Numerically-stable softplus matching jax.nn.softplus
__device__ __forceinline__ float softplus(float x) {
    return fmaxf(x, 0.0f) + log1pf(__expf(-fabsf(x)));
}

__device__ __forceinline__ float dot4(float4 a, float4 b) {
    return fmaf(a.x, b.x, fmaf(a.y, b.y, fmaf(a.z, b.z, a.w * b.w)));
}

// c ? a : b, componentwise (v_cndmask x4 off a precomputed vcc)
__device__ __forceinline__ float4 sel4(bool c, float4 a, float4 b) {
    float4 r;
    r.x = c ? a.x : b.x;  r.y = c ? a.y : b.y;
    r.z = c ? a.z : b.z;  r.w = c ? a.w : b.w;
    return r;
}

// swap halves of the wave (lane ^ 32), componentwise
__device__ __forceinline__ float4 swap32(float4 v) {
    float4 r;
    r.x = __shfl_xor(v.x, 32);  r.y = __shfl_xor(v.y, 32);
    r.z = __shfl_xor(v.z, 32);  r.w = __shfl_xor(v.w, 32);
    return r;
}

// Paired-row gather: lanes 0-31 get row i0, lanes 32-63 get row i1.
// One global_load_dwordx4 per lane = 1 KB per wave-load (2 embed rows).
__device__ __forceinline__ float4 pload(const float* ebase, bool half, int i0, int i1) {
    const int idx = half ? i1 : i0;
    return *(const float4*)(ebase + (size_t)idx * D);
}

__global__ __launch_bounds__(256, 4) void sg_partial(
    const int* __restrict__ walk, const int* __restrict__ neg,
    const float* __restrict__ embed, float* __restrict__ ws)
{
    __shared__ float s_wsum[WAVES_PER_BLOCK];
    const int tid  = threadIdx.x;
    const int lane = tid & 63;
    const int l32  = lane & 31;
    const bool half = lane >= 32;           // which 32-lane half owns this fragment
    // force wave id into an SGPR so all index loads scalarize (s_load)
    const int wave = __builtin_amdgcn_readfirstlane(tid >> 6);
    const int b    = blockIdx.x;
    const int a0   = wave * PAIRS_PER_WAVE;

    const float* ebase = embed + l32 * 4;   // this lane's float4 slot within a row
    const int*   wrow  = walk + b * LW + a0;                  // wave-uniform
    const int*   nrow  = neg + (size_t)(b * AA + a0) * NEGS;  // wave-uniform

    // Window registers hold ROW PAIRS: w01 = rows (2d, 2d+1), w23 = (2d+2, 2d+3),
    // w45 = (2d+4, 2d+5); low half of the wave holds the even row, high half the odd.
    float4 w01 = pload(ebase, half, wrow[0], wrow[1]);
    float4 w23 = pload(ebase, half, wrow[2], wrow[3]);
    float4 w45 = pload(ebase, half, wrow[4], wrow[5]);

    int4 nva = *(const int4*)(nrow);        // uniform -> s_load_dwordx4
    int4 nvb = *(const int4*)(nrow + 4);
    float4 n01 = pload(ebase, half, nva.x, nva.y);   // negs of anchor 2d
    float4 n23 = pload(ebase, half, nva.z, nva.w);
    float4 n45 = pload(ebase, half, nvb.x, nvb.y);   // negs of anchor 2d+1
    float4 n67 = pload(ebase, half, nvb.z, nvb.w);

    const bool hi1 = lane & 1;
    const bool hi2 = lane & 2;
    const bool hi3 = lane & 4;

    float wsum = 0.0f;   // main loop (replication x4 per logit)
    float tsum = 0.0f;   // tail pair  (replication x8 per logit)

    // 9 double-steps: anchors (2d, 2d+1), d = 0..8  (18 anchors), + 1 tail anchor.
    #pragma unroll
    for (int d = 0; d < 9; ++d) {
        // ---- prefetch next step's rows (5 gathers) before computing current ----
        float4 nw, m01, m23, m45, m67;
        if (d < 8) {
            nw = pload(ebase, half, wrow[2*d + 6], wrow[2*d + 7]);
            const int4 pa = *(const int4*)(nrow + 8*(d + 1));
            const int4 pb = *(const int4*)(nrow + 8*(d + 1) + 4);
            m01 = pload(ebase, half, pa.x, pa.y);
            m23 = pload(ebase, half, pa.z, pa.w);
            m45 = pload(ebase, half, pb.x, pb.y);
            m67 = pload(ebase, half, pb.z, pb.w);
        } else {
            // tail prefetch: window row 22 (row 23 never used; avoid OOB read at
            // b=1023, wave 3 where a0+23 == 80) and tail anchor's 4 negs.
            const int i22 = wrow[22];
            nw = pload(ebase, half, i22, i22);
            const int4 pa = *(const int4*)(nrow + 72);
            m01 = pload(ebase, half, pa.x, pa.y);
            m23 = pload(ebase, half, pa.z, pa.w);
            m45 = m01;  m67 = m23;   // unused in tail; keep defined
        }

        // ---- compute current double-step ----
        // X = w01 (lane-local frag), Y = halves-swapped w01.
        // Z0 = anchor(2d)'s frag in this lane; Z1 = anchor(2d+1)'s frag.
        const float4 Y   = swap32(w01);
        const float4 Z0  = sel4(half, Y, w01);
        const float4 Z1  = sel4(half, w01, Y);
        const float4 Aop = sel4(half, w01, w23);   // pos row (2d+1 | 2d+2) per half
        const float4 Bop = sel4(half, w23, w45);   // pos row (2d+3 | 2d+4) per half

        // 8 partial dot-products per lane; per half they mean:
        //   half0: L(0,2) L(0,4) L(1,2) L(1,4) | L(0,n0) L(0,n2) L(1,n4) L(1,n6)
        //   half1: L(0,1) L(0,3) L(1,3) L(1,5) | L(0,n1) L(0,n3) L(1,n5) L(1,n7)
        // a0..a3 = pos, a4..a7 = neg -> final logit id from lane bits, neg iff bit0.
        const float a0v = dot4(Z0, Aop);
        const float a1v = dot4(Z0, Bop);
        const float a2v = dot4(Z1, w23);
        const float a3v = dot4(Z1, w45);
        const float a4v = dot4(Z0, n01);
        const float a5v = dot4(Z0, n23);
        const float a6v = dot4(Z1, n45);
        const float a7v = dot4(Z1, n67);

        // reduce-scatter butterfly WITHIN each 32-lane half (halves hold
        // different logits): 4+2+1 scatter stages + xor8 + xor16 = 9 shuffles.
        float b0 = (hi1 ? a4v : a0v) + __shfl_xor(hi1 ? a0v : a4v, 1);
        float b1 = (hi1 ? a5v : a1v) + __shfl_xor(hi1 ? a1v : a5v, 1);
        float b2 = (hi1 ? a6v : a2v) + __shfl_xor(hi1 ? a2v : a6v, 1);
        float b3 = (hi1 ? a7v : a3v) + __shfl_xor(hi1 ? a3v : a7v, 1);

        float c0 = (hi2 ? b2 : b0) + __shfl_xor(hi2 ? b0 : b2, 2);
        float c1 = (hi2 ? b3 : b1) + __shfl_xor(hi2 ? b1 : b3, 2);

        float dv = (hi3 ? c1 : c0) + __shfl_xor(hi3 ? c0 : c1, 4);
        dv += __shfl_xor(dv, 8);
        dv += __shfl_xor(dv, 16);
        // dv = fully-reduced logit (4x replicated per half). neg iff bit0.
        wsum += softplus(hi1 ? dv : -dv);

        // ---- slide window by 2 rows, rotate neg buffers ----
        w01 = w23;  w23 = w45;  w45 = nw;
        n01 = m01;  n23 = m23;  n45 = m45;  n67 = m67;
    }

    // ---- tail anchor (index 18): rows 18..22 in w01..w45, negs in n01/n23 ----
    {
        const float4 Y   = swap32(w01);
        const float4 Z0  = sel4(half, Y, w01);          // anchor 18's frag
        const float4 Aop = sel4(half, w01, w23);        // pos row (19 | 20)
        const float4 Bop = sel4(half, w23, w45);        // pos row (21 | 22)

        // per lane: t0,t1 = pos, t2,t3 = neg; id from lane bits, neg iff bit0
        const float t0 = dot4(Z0, Aop);
        const float t1 = dot4(Z0, Bop);
        const float t2 = dot4(Z0, n01);
        const float t3 = dot4(Z0, n23);

        float u0 = (hi1 ? t2 : t0) + __shfl_xor(hi1 ? t0 : t2, 1);
        float u1 = (hi1 ? t3 : t1) + __shfl_xor(hi1 ? t1 : t3, 1);
        float v  = (hi2 ? u1 : u0) + __shfl_xor(hi2 ? u0 : u1, 2);
        v += __shfl_xor(v, 4);
        v += __shfl_xor(v, 8);
        v += __shfl_xor(v, 16);
        tsum = softplus(hi1 ? v : -v);                  // 8x replicated per half
    }

    // main logits counted 4x, tail logits 8x -> normalize to 1x per logit
    float tot = wsum + 0.5f * tsum;
    #pragma unroll
    for (int m = 1; m < 64; m <<= 1) tot += __shfl_xor(tot, m);

    if (lane == 0) s_wsum[wave] = tot * 0.25f;
    __syncthreads();
    if (tid == 0)
        ws[blockIdx.x] = s_wsum[0] + s_wsum[1] + s_wsum[2] + s_wsum[3];
}

__global__ __launch_bounds__(256) void sg_reduce(
    const float* __restrict__ ws, float* __restrict__ out)
{
    __shared__ float s[4];
    const int tid = threadIdx.x;
    float sum = 0.0f;
    #pragma unroll
    for (int i = 0; i < NBLOCKS / 256; ++i) sum += ws[tid + i * 256];
    #pragma unroll
    for (int m = 1; m < 64; m <<= 1) sum += __shfl_xor(sum, m);
    const int wave = tid >> 6;
    const int lane = tid & 63;
    if (lane == 0) s[wave] = sum;
    __syncthreads();
    if (tid == 0) {
        const float total = (float)((size_t)PAIRS * 8);   // 622592 logits
        out[0] = (s[0] + s[1] + s[2] + s[3]) * (1.0f / total);
    }
}

extern "C" void kernel_launch(void* const* d_in, const int* in_sizes, int n_in,
                              void* d_out, int out_size, void* d_ws, size_t ws_size,
                              hipStream_t stream) {
    const int*   walk  = (const int*)d_in[0];
    const int*   neg   = (const int*)d_in[1];
    const float* embed = (const float*)d_in[2];
    float* ws  = (float*)d_ws;   // NBLOCKS floats of scratch (4 KB)
    float* out = (float*)d_out;

    sg_partial<<<NBLOCKS, 256, 0, stream>>>(walk, neg, embed, ws);
    sg_reduce<<<1, 256, 0, stream>>>(ws, out);
}